// Round 6
// baseline (910.437 us; speedup 1.0000x reference)
//
#include <hip/hip_runtime.h>

typedef __bf16 bf16;
typedef __bf16 bf16x8 __attribute__((ext_vector_type(8)));
typedef float floatx4 __attribute__((ext_vector_type(4)));

#define N_NODES 50000
#define N_EDGES 800000
#define SX 136  // X row stride in bf16 (272 B = 17*16: aligned, dword-stride 68 === 4 mod 32)

__device__ __forceinline__ float silu_f(float x) {
  float t = fminf(fmaxf(x, -40.f), 40.f);
  return x / (1.f + __expf(-t));
}
__device__ __forceinline__ float sigm_f(float x) {
  float t = fminf(fmaxf(x, -40.f), 40.f);
  return 1.f / (1.f + __expf(-t));
}

// ---------------- prep: f32 -> bf16 ----------------
__global__ void prep_nf(const float* __restrict__ src, bf16* __restrict__ dst) {
  int i = (blockIdx.x * 256 + threadIdx.x) * 4;
  float4 v = *(const float4*)(src + i);
  bf16 o[4] = {(bf16)v.x, (bf16)v.y, (bf16)v.z, (bf16)v.w};
  *(float2*)(dst + i) = *(float2*)o;
}

// transpose+convert weights: Wt[n*Kp + k] = W[k*128 + n], zero-padded to Kp
struct TW { const float* s[5]; int K[5]; int Kp[5]; int off[5]; };
__global__ void prep_tw(TW j, bf16* __restrict__ out) {
  int g = blockIdx.x * 256 + threadIdx.x;
#pragma unroll
  for (int t = 0; t < 5; ++t) {
    int sz = 128 * j.Kp[t];
    if (g < sz) {
      int n = g / j.Kp[t], k = g - n * j.Kp[t];
      out[j.off[t] + g] = (k < j.K[t]) ? (bf16)j.s[t][(size_t)k * 128 + n] : (bf16)0.f;
      return;
    }
    g -= sz;
  }
}

__device__ __forceinline__ floatx4 MF(bf16x8 a, bf16x8 b, floatx4 c) {
  return __builtin_amdgcn_mfma_f32_16x16x32_bf16(a, b, c, 0, 0, 0);
}

// one 32-wide k-step over 8 col-tiles; B straight from global (L2-resident Wt),
// each B fragment shared by 4 row-subtiles.
__device__ __forceinline__ void step8(const bf16* __restrict__ Wt, int Kp, int kidx,
                                      int l15, int quad, const bf16x8 a[4],
                                      floatx4 acc[4][8]) {
#pragma unroll
  for (int nt = 0; nt < 8; ++nt) {
    bf16x8 b = *(const bf16x8*)(Wt + (size_t)(nt * 16 + l15) * Kp + kidx + quad * 8);
#pragma unroll
    for (int t = 0; t < 4; ++t) acc[t][nt] = MF(a[t], b, acc[t][nt]);
  }
}

// ---------------- edge kernel: 256 edges/block, 64 rows/wave, ZERO barriers ----------------
// All LDS (X, cdL, radL, sIdx, dIdx) is indexed only by rows owned by the same wave
// (tid == row in phase 0), so no __syncthreads is needed anywhere.
__global__ __launch_bounds__(256, 2) void edge_kernel(
    const bf16* __restrict__ nfb, const float* __restrict__ coords,
    const float* __restrict__ ef,
    const bf16* __restrict__ We1t, const float* __restrict__ be1,
    const bf16* __restrict__ We2t, const float* __restrict__ be2,
    const bf16* __restrict__ Wc1t, const float* __restrict__ bc1,
    const float* __restrict__ Wc, const float* __restrict__ Wa,
    const float* __restrict__ ba,
    const int* __restrict__ src, const int* __restrict__ dst,
    float* __restrict__ m_agg, float* __restrict__ agg, float* __restrict__ cnt) {
  __shared__ __align__(16) bf16 X[256 * SX];   // h1, then gated m (rows wave-private)
  __shared__ float cdL[256][3];
  __shared__ float radL[256];
  __shared__ int sIdx[256], dIdx[256];

  const int tid = threadIdx.x;
  const int lane = tid & 63;
  const int wv = tid >> 6;
  const int l15 = lane & 15;
  const int quad = lane >> 4;
  const int r0 = wv * 64;
  const int e0 = blockIdx.x * 256;

  // phase 0: tid == row, wave-private
  {
    int e = e0 + tid;
    int s = src[e], d = dst[e];
    if ((unsigned)s >= N_NODES) s = 0;
    if ((unsigned)d >= N_NODES) d = 0;
    sIdx[tid] = s; dIdx[tid] = d;
    float dx = coords[s * 3 + 0] - coords[d * 3 + 0];
    float dy = coords[s * 3 + 1] - coords[d * 3 + 1];
    float dz = coords[s * 3 + 2] - coords[d * 3 + 2];
    cdL[tid][0] = dx; cdL[tid][1] = dy; cdL[tid][2] = dz;
    radL[tid] = dx * dx + dy * dy + dz * dz;
  }

  const floatx4 z4 = {0.f, 0.f, 0.f, 0.f};
  floatx4 acc[4][8];
#pragma unroll
  for (int t = 0; t < 4; ++t)
#pragma unroll
    for (int nt = 0; nt < 8; ++nt) acc[t][nt] = z4;

  // ---- layer e1: kc 0..3 = h_src|h_dst gathers ----
#pragma unroll
  for (int kc = 0; kc < 4; ++kc) {
    const int* idx = (kc < 2) ? sIdx : dIdx;
    int nd[4];
#pragma unroll
    for (int t = 0; t < 4; ++t) nd[t] = idx[r0 + t * 16 + l15];
#pragma unroll
    for (int s = 0; s < 2; ++s) {
      bf16x8 a[4];
#pragma unroll
      for (int t = 0; t < 4; ++t)
        a[t] = *(const bf16x8*)(nfb + (size_t)nd[t] * 128 + (kc & 1) * 64 + s * 32 + quad * 8);
      step8(We1t, 320, kc * 64 + s * 32, l15, quad, a, acc);
    }
  }
  // kc=4: [radial | ef(32) | zeros] built in registers
#pragma unroll
  for (int s = 0; s < 2; ++s) {
    bf16x8 a[4];
#pragma unroll
    for (int t = 0; t < 4; ++t) {
      int row = r0 + t * 16 + l15;
#pragma unroll
      for (int jj = 0; jj < 8; ++jj) {
        int k = s * 32 + quad * 8 + jj;
        float v = 0.f;
        if (k == 0) v = radL[row];
        else if (k <= 32) v = ef[(size_t)(e0 + row) * 32 + (k - 1)];
        a[t][jj] = (bf16)v;
      }
    }
    step8(We1t, 320, 256 + s * 32, l15, quad, a, acc);
  }
  // epilogue e1: h1 -> X
#pragma unroll
  for (int t = 0; t < 4; ++t)
#pragma unroll
    for (int nt = 0; nt < 8; ++nt) {
      int col = nt * 16 + l15;
      float b = be1[col];
#pragma unroll
      for (int i = 0; i < 4; ++i) {
        X[(r0 + t * 16 + quad * 4 + i) * SX + col] = (bf16)silu_f(acc[t][nt][i] + b);
        acc[t][nt][i] = 0.f;
      }
    }

  // ---- layer e2: K=128, A from X ----
#pragma unroll
  for (int kc = 0; kc < 2; ++kc)
#pragma unroll
    for (int s = 0; s < 2; ++s) {
      bf16x8 a[4];
#pragma unroll
      for (int t = 0; t < 4; ++t)
        a[t] = *(const bf16x8*)(X + (r0 + t * 16 + l15) * SX + kc * 64 + s * 32 + quad * 8);
      step8(We2t, 128, kc * 64 + s * 32, l15, quad, a, acc);
    }
  // epilogue e2: silu + attention gate, write gated m to X, scatter m_agg
  float part[4][4];
#pragma unroll
  for (int t = 0; t < 4; ++t)
#pragma unroll
    for (int i = 0; i < 4; ++i) part[t][i] = 0.f;
#pragma unroll
  for (int t = 0; t < 4; ++t)
#pragma unroll
    for (int nt = 0; nt < 8; ++nt) {
      int col = nt * 16 + l15;
      float b = be2[col], wa = Wa[col];
#pragma unroll
      for (int i = 0; i < 4; ++i) {
        float v = silu_f(acc[t][nt][i] + b);
        acc[t][nt][i] = v;
        part[t][i] += v * wa;
      }
    }
#pragma unroll
  for (int off = 1; off < 16; off <<= 1)
#pragma unroll
    for (int t = 0; t < 4; ++t)
#pragma unroll
      for (int i = 0; i < 4; ++i) part[t][i] += __shfl_xor(part[t][i], off, 64);
  float ba_f = ba[0];
#pragma unroll
  for (int t = 0; t < 4; ++t)
#pragma unroll
    for (int i = 0; i < 4; ++i) {
      float g = sigm_f(part[t][i] + ba_f);
#pragma unroll
      for (int nt = 0; nt < 8; ++nt) acc[t][nt][i] *= g;
    }
#pragma unroll
  for (int t = 0; t < 4; ++t)
#pragma unroll
    for (int nt = 0; nt < 8; ++nt) {
      int col = nt * 16 + l15;
#pragma unroll
      for (int i = 0; i < 4; ++i)
        X[(r0 + t * 16 + quad * 4 + i) * SX + col] = (bf16)acc[t][nt][i];
    }
  // scatter gated m (f32 atomics)
#pragma unroll
  for (int t = 0; t < 4; ++t)
#pragma unroll
    for (int i = 0; i < 4; ++i) {
      size_t base = (size_t)dIdx[r0 + t * 16 + quad * 4 + i] * 128;
#pragma unroll
      for (int nt = 0; nt < 8; ++nt)
        atomicAdd(&m_agg[base + nt * 16 + l15], acc[t][nt][i]);
    }
#pragma unroll
  for (int t = 0; t < 4; ++t)
#pragma unroll
    for (int nt = 0; nt < 8; ++nt) acc[t][nt] = z4;

  // ---- coord layer: K=128, A = gated m from X ----
#pragma unroll
  for (int kc = 0; kc < 2; ++kc)
#pragma unroll
    for (int s = 0; s < 2; ++s) {
      bf16x8 a[4];
#pragma unroll
      for (int t = 0; t < 4; ++t)
        a[t] = *(const bf16x8*)(X + (r0 + t * 16 + l15) * SX + kc * 64 + s * 32 + quad * 8);
      step8(Wc1t, 128, kc * 64 + s * 32, l15, quad, a, acc);
    }
  float partc[4][4];
#pragma unroll
  for (int t = 0; t < 4; ++t)
#pragma unroll
    for (int i = 0; i < 4; ++i) partc[t][i] = 0.f;
#pragma unroll
  for (int t = 0; t < 4; ++t)
#pragma unroll
    for (int nt = 0; nt < 8; ++nt) {
      int col = nt * 16 + l15;
      float b = bc1[col], wc = Wc[col];
#pragma unroll
      for (int i = 0; i < 4; ++i) partc[t][i] += silu_f(acc[t][nt][i] + b) * wc;
    }
#pragma unroll
  for (int off = 1; off < 16; off <<= 1)
#pragma unroll
    for (int t = 0; t < 4; ++t)
#pragma unroll
      for (int i = 0; i < 4; ++i) partc[t][i] += __shfl_xor(partc[t][i], off, 64);
  if (l15 == 0) {
#pragma unroll
    for (int t = 0; t < 4; ++t)
#pragma unroll
      for (int i = 0; i < 4; ++i) {
        int row = r0 + t * 16 + quad * 4 + i;
        int d = dIdx[row];
        float c = partc[t][i];
        atomicAdd(&agg[d * 3 + 0], cdL[row][0] * c);
        atomicAdd(&agg[d * 3 + 1], cdL[row][1] * c);
        atomicAdd(&agg[d * 3 + 2], cdL[row][2] * c);
        atomicAdd(&cnt[d], 1.0f);
      }
  }
}

// ---------------- node kernel: 256 nodes/block, barrier-free ----------------
__global__ __launch_bounds__(256, 2) void node_kernel(
    const bf16* __restrict__ nfb, const float* __restrict__ nf,
    const float* __restrict__ coords,
    const bf16* __restrict__ Wn1t, const float* __restrict__ bn1,
    const bf16* __restrict__ Wn2t, const float* __restrict__ bn2,
    const float* __restrict__ m_agg, const float* __restrict__ agg,
    const float* __restrict__ cnt,
    float* __restrict__ h_out, float* __restrict__ c_out) {
  __shared__ __align__(16) bf16 X[256 * SX];

  const int tid = threadIdx.x;
  const int lane = tid & 63;
  const int wv = tid >> 6;
  const int l15 = lane & 15;
  const int quad = lane >> 4;
  const int r0 = wv * 64;
  const int n0 = blockIdx.x * 256;

  {
    int n = n0 + tid;
    if (n < N_NODES) {
      float inv = 1.f / fmaxf(cnt[n], 1.f);
#pragma unroll
      for (int j = 0; j < 3; ++j)
        c_out[n * 3 + j] = coords[n * 3 + j] + agg[n * 3 + j] * inv;
    }
  }

  const floatx4 z4 = {0.f, 0.f, 0.f, 0.f};
  floatx4 acc[4][8];
#pragma unroll
  for (int t = 0; t < 4; ++t)
#pragma unroll
    for (int nt = 0; nt < 8; ++nt) acc[t][nt] = z4;

  // ---- n1: K=256 (h | m_agg) ----
#pragma unroll
  for (int kc = 0; kc < 4; ++kc)
#pragma unroll
    for (int s = 0; s < 2; ++s) {
      bf16x8 a[4];
#pragma unroll
      for (int t = 0; t < 4; ++t) {
        int n = n0 + r0 + t * 16 + l15;
        int nc = (n < N_NODES) ? n : 0;
        if (kc < 2) {
          a[t] = *(const bf16x8*)(nfb + (size_t)nc * 128 + kc * 64 + s * 32 + quad * 8);
        } else {
          const float* p = m_agg + (size_t)nc * 128 + (kc - 2) * 64 + s * 32 + quad * 8;
          float4 u0 = *(const float4*)(p);
          float4 u1 = *(const float4*)(p + 4);
          bf16x8 f;
          f[0] = (bf16)u0.x; f[1] = (bf16)u0.y; f[2] = (bf16)u0.z; f[3] = (bf16)u0.w;
          f[4] = (bf16)u1.x; f[5] = (bf16)u1.y; f[6] = (bf16)u1.z; f[7] = (bf16)u1.w;
          a[t] = f;
        }
      }
      step8(Wn1t, 256, kc * 64 + s * 32, l15, quad, a, acc);
    }
#pragma unroll
  for (int t = 0; t < 4; ++t)
#pragma unroll
    for (int nt = 0; nt < 8; ++nt) {
      int col = nt * 16 + l15;
      float b = bn1[col];
#pragma unroll
      for (int i = 0; i < 4; ++i) {
        X[(r0 + t * 16 + quad * 4 + i) * SX + col] = (bf16)silu_f(acc[t][nt][i] + b);
        acc[t][nt][i] = 0.f;
      }
    }

  // ---- n2: K=128, A = h1 from X; residual from f32 nf ----
#pragma unroll
  for (int kc = 0; kc < 2; ++kc)
#pragma unroll
    for (int s = 0; s < 2; ++s) {
      bf16x8 a[4];
#pragma unroll
      for (int t = 0; t < 4; ++t)
        a[t] = *(const bf16x8*)(X + (r0 + t * 16 + l15) * SX + kc * 64 + s * 32 + quad * 8);
      step8(Wn2t, 128, kc * 64 + s * 32, l15, quad, a, acc);
    }
#pragma unroll
  for (int t = 0; t < 4; ++t)
#pragma unroll
    for (int nt = 0; nt < 8; ++nt) {
      int col = nt * 16 + l15;
      float b = bn2[col];
#pragma unroll
      for (int i = 0; i < 4; ++i) {
        int n = n0 + r0 + t * 16 + quad * 4 + i;
        if (n < N_NODES)
          h_out[(size_t)n * 128 + col] = nf[(size_t)n * 128 + col] + acc[t][nt][i] + b;
      }
    }
}

extern "C" void kernel_launch(void* const* d_in, const int* in_sizes, int n_in,
                              void* d_out, int out_size, void* d_ws, size_t ws_size,
                              hipStream_t stream) {
  const float* nf     = (const float*)d_in[0];
  const float* coords = (const float*)d_in[1];
  const float* ef     = (const float*)d_in[2];
  const float* We1    = (const float*)d_in[3];
  const float* be1    = (const float*)d_in[4];
  const float* We2    = (const float*)d_in[5];
  const float* be2    = (const float*)d_in[6];
  const float* Wn1    = (const float*)d_in[7];
  const float* bn1    = (const float*)d_in[8];
  const float* Wn2    = (const float*)d_in[9];
  const float* bn2    = (const float*)d_in[10];
  const float* Wc1    = (const float*)d_in[11];
  const float* bc1    = (const float*)d_in[12];
  const float* Wc     = (const float*)d_in[13];
  const float* Wa     = (const float*)d_in[14];
  const float* ba     = (const float*)d_in[15];
  const int*   src    = (const int*)d_in[16];
  const int*   dst    = (const int*)d_in[17];

  float* agg   = (float*)d_ws;                      // 3N
  float* cnt   = agg + (size_t)3 * N_NODES;         // N
  float* m_agg = cnt + N_NODES;                     // N*128
  bf16* nfb    = (bf16*)(m_agg + (size_t)N_NODES * 128);
  bf16* Wt     = nfb + (size_t)N_NODES * 128;       // 122880 bf16
  const int offE1 = 0;
  const int offE2 = 128 * 320;
  const int offC1 = offE2 + 128 * 128;
  const int offN1 = offC1 + 128 * 128;
  const int offN2 = offN1 + 128 * 256;

  size_t zb = ((size_t)3 * N_NODES + N_NODES + (size_t)N_NODES * 128) * sizeof(float);
  hipMemsetAsync(d_ws, 0, zb, stream);

  prep_nf<<<(N_NODES * 128) / (256 * 4), 256, 0, stream>>>(nf, nfb);
  TW tw;
  tw.s[0] = We1; tw.K[0] = 289; tw.Kp[0] = 320; tw.off[0] = offE1;
  tw.s[1] = We2; tw.K[1] = 128; tw.Kp[1] = 128; tw.off[1] = offE2;
  tw.s[2] = Wc1; tw.K[2] = 128; tw.Kp[2] = 128; tw.off[2] = offC1;
  tw.s[3] = Wn1; tw.K[3] = 256; tw.Kp[3] = 256; tw.off[3] = offN1;
  tw.s[4] = Wn2; tw.K[4] = 128; tw.Kp[4] = 128; tw.off[4] = offN2;
  prep_tw<<<480, 256, 0, stream>>>(tw, Wt);

  float* h_out = (float*)d_out;
  float* c_out = h_out + (size_t)N_NODES * 128;

  edge_kernel<<<N_EDGES / 256, 256, 0, stream>>>(
      nfb, coords, ef, Wt + offE1, be1, Wt + offE2, be2, Wt + offC1, bc1,
      Wc, Wa, ba, src, dst, m_agg, agg, cnt);
  node_kernel<<<(N_NODES + 255) / 256, 256, 0, stream>>>(
      nfb, nf, coords, Wt + offN1, bn1, Wt + offN2, bn2,
      m_agg, agg, cnt, h_out, c_out);
}

// Round 7
// 778.711 us; speedup vs baseline: 1.1692x; 1.1692x over previous
//
#include <hip/hip_runtime.h>

typedef __bf16 bf16;
typedef __bf16 bf16x8 __attribute__((ext_vector_type(8)));
typedef float floatx4 __attribute__((ext_vector_type(4)));

#define N_NODES 50000
#define N_EDGES 800000

// light barrier: drain LDS ops only; global loads/atomics stay in flight (CK block_sync_lds)
#define SYNC() asm volatile("s_waitcnt lgkmcnt(0)\n\ts_barrier" ::: "memory")

__device__ __forceinline__ float silu_f(float x) {
  float t = fminf(fmaxf(x, -40.f), 40.f);
  return x / (1.f + __expf(-t));
}
__device__ __forceinline__ float sigm_f(float x) {
  float t = fminf(fmaxf(x, -40.f), 40.f);
  return 1.f / (1.f + __expf(-t));
}

__device__ __forceinline__ floatx4 MF(bf16x8 a, bf16x8 b, floatx4 c) {
  return __builtin_amdgcn_mfma_f32_16x16x32_bf16(a, b, c, 0, 0, 0);
}

// ---------------- prep ----------------
__global__ void prep_nf(const float* __restrict__ src, bf16* __restrict__ dst) {
  int i = (blockIdx.x * 256 + threadIdx.x) * 4;
  float4 v = *(const float4*)(src + i);
  bf16 o[4] = {(bf16)v.x, (bf16)v.y, (bf16)v.z, (bf16)v.w};
  *(float2*)(dst + i) = *(float2*)o;
}

struct TW { const float* s[5]; int K[5]; int Kp[5]; int off[5]; };
__global__ void prep_tw(TW j, bf16* __restrict__ out) {
  int g = blockIdx.x * 256 + threadIdx.x;
#pragma unroll
  for (int t = 0; t < 5; ++t) {
    int sz = 128 * j.Kp[t];
    if (g < sz) {
      int n = g / j.Kp[t], k = g - n * j.Kp[t];
      out[j.off[t] + g] = (k < j.K[t]) ? (bf16)j.s[t][(size_t)k * 128 + n] : (bf16)0.f;
      return;
    }
    g -= sz;
  }
}

// one 32-wide chunk: 8 swizzled b128 B-reads from LDS, 16 MFMAs (2 row-subtiles)
__device__ __forceinline__ void chunk_mfma(const bf16* __restrict__ Wb, int l15, int quad,
                                           bf16x8 a0, bf16x8 a1, floatx4 acc[2][8]) {
#pragma unroll
  for (int nt = 0; nt < 8; ++nt) {
    bf16x8 b = *(const bf16x8*)(Wb + (nt * 16 + l15) * 32 + ((quad ^ (l15 & 3)) << 3));
    acc[0][nt] = MF(a0, b, acc[0][nt]);
    acc[1][nt] = MF(a1, b, acc[1][nt]);
  }
}

// ---------------- edge kernel: 128 edges/block, 4 waves x 32 rows ----------------
__global__ __launch_bounds__(256, 3) void edge_kernel(
    const bf16* __restrict__ nfb, const float* __restrict__ coords,
    const float* __restrict__ ef,
    const bf16* __restrict__ We1t, const float* __restrict__ be1,
    const bf16* __restrict__ We2t, const float* __restrict__ be2,
    const bf16* __restrict__ Wc1t, const float* __restrict__ bc1,
    const float* __restrict__ Wc, const float* __restrict__ Wa,
    const float* __restrict__ ba,
    const int* __restrict__ src, const int* __restrict__ dst,
    float* __restrict__ m_agg, float* __restrict__ agg, float* __restrict__ cnt) {
  __shared__ __align__(16) bf16 X[128 * 128];     // swizzled activations (rows wave-private)
  __shared__ __align__(16) bf16 Wl[2 * 4096];     // double-buffered 32-wide W chunk
  __shared__ int sIdx[128], dIdx[128];
  __shared__ float cdL[128][3];
  __shared__ float radL[128];

  const int tid = threadIdx.x;
  const int lane = tid & 63;
  const int wv = tid >> 6;
  const int l15 = lane & 15;
  const int quad = lane >> 4;
  const int r0 = wv * 32;
  const int e0 = blockIdx.x * 128;

  // phase 0: wave-private (lanes 0..31 of each wave own rows r0..r0+31)
  if (!(lane & 32)) {
    int row = r0 + (lane & 31);
    int e = e0 + row;
    int s = src[e], d = dst[e];
    if ((unsigned)s >= N_NODES) s = 0;
    if ((unsigned)d >= N_NODES) d = 0;
    sIdx[row] = s; dIdx[row] = d;
    float dx = coords[s * 3 + 0] - coords[d * 3 + 0];
    float dy = coords[s * 3 + 1] - coords[d * 3 + 1];
    float dz = coords[s * 3 + 2] - coords[d * 3 + 2];
    cdL[row][0] = dx; cdL[row][1] = dy; cdL[row][2] = dz;
    radL[row] = dx * dx + dy * dy + dz * dz;
  }

  // W staging: per thread 2 x b128 (rows n0 and n0+64), XOR-swizzled chunk-of-4
  const int n0 = tid >> 2, c4 = tid & 3;
  const int swz8 = (c4 ^ (n0 & 3)) << 3;
  bf16* w0p = Wl + n0 * 32 + swz8;
  bf16* w1p = Wl + (n0 + 64) * 32 + swz8;
  float4 wb0, wb1;
  auto wload = [&](const bf16* base, int Kp, int ko) {
    wb0 = *(const float4*)(base + (size_t)n0 * Kp + ko + c4 * 8);
    wb1 = *(const float4*)(base + (size_t)(n0 + 64) * Kp + ko + c4 * 8);
  };
  auto wstore = [&](int buf) {
    *(float4*)(w0p + buf * 4096) = wb0;
    *(float4*)(w1p + buf * 4096) = wb1;
  };

  auto loadA = [&](int c, bf16x8 a[2]) {
    if (c < 8) {
      const int* idx = (c < 4) ? sIdx : dIdx;
#pragma unroll
      for (int t = 0; t < 2; ++t) {
        int node = idx[r0 + t * 16 + l15];
        a[t] = *(const bf16x8*)(nfb + (size_t)node * 128 + (c & 3) * 32 + quad * 8);
      }
    } else {
      int s = c - 8;
#pragma unroll
      for (int t = 0; t < 2; ++t) {
        int row = r0 + t * 16 + l15;
#pragma unroll
        for (int j = 0; j < 8; ++j) {
          int k = s * 32 + quad * 8 + j;
          float v = 0.f;
          if (k == 0) v = radL[row];
          else if (k <= 32) v = ef[(size_t)(e0 + row) * 32 + (k - 1)];
          a[t][j] = (bf16)v;
        }
      }
    }
  };
  auto xread = [&](int c, bf16x8 a[2]) {
#pragma unroll
    for (int t = 0; t < 2; ++t) {
      int row = r0 + t * 16 + l15;
      a[t] = *(const bf16x8*)(X + row * 128 + ((((c * 4) + quad) ^ l15) << 3));
    }
  };
  auto xwrite = [&](int t, int nt, int i, float v) {
    int R = r0 + t * 16 + quad * 4 + i;
    int col = nt * 16 + l15;
    X[R * 128 + ((((col >> 3) ^ (R & 15))) << 3) + (col & 7)] = (bf16)v;
  };

  const floatx4 z4 = {0.f, 0.f, 0.f, 0.f};
  floatx4 acc[2][8];
#pragma unroll
  for (int t = 0; t < 2; ++t)
#pragma unroll
    for (int nt = 0; nt < 8; ++nt) acc[t][nt] = z4;

  bf16x8 aC[2], aN[2];

  // ---- layer e1: K=320, 10 chunks of 32, dbuf pipeline ----
  wload(We1t, 320, 0);
  wstore(0);
  loadA(0, aC);
  SYNC();
#pragma unroll
  for (int c = 0; c < 10; ++c) {
    if (c + 1 < 10) { wload(We1t, 320, (c + 1) * 32); loadA(c + 1, aN); }
    else            { wload(We2t, 128, 0); }      // cross-layer W prefetch
    chunk_mfma(Wl + (c & 1) * 4096, l15, quad, aC[0], aC[1], acc);
    wstore((c + 1) & 1);
    SYNC();
    aC[0] = aN[0]; aC[1] = aN[1];
  }
  // epilogue e1: h1 -> X
#pragma unroll
  for (int t = 0; t < 2; ++t)
#pragma unroll
    for (int nt = 0; nt < 8; ++nt) {
      float b = be1[nt * 16 + l15];
#pragma unroll
      for (int i = 0; i < 4; ++i) {
        xwrite(t, nt, i, silu_f(acc[t][nt][i] + b));
        acc[t][nt][i] = 0.f;
      }
    }

  // ---- layer e2: K=128, 4 chunks (global chunk ids 10..13) ----
#pragma unroll
  for (int c = 0; c < 4; ++c) {
    int gi = 10 + c;
    if (c + 1 < 4) wload(We2t, 128, (c + 1) * 32);
    else           wload(Wc1t, 128, 0);
    xread(c, aC);
    chunk_mfma(Wl + (gi & 1) * 4096, l15, quad, aC[0], aC[1], acc);
    wstore((gi + 1) & 1);
    SYNC();
  }
  // epilogue e2: silu + attention gate; gated m -> X + atomic scatter
  float part[2][4];
#pragma unroll
  for (int t = 0; t < 2; ++t)
#pragma unroll
    for (int i = 0; i < 4; ++i) part[t][i] = 0.f;
#pragma unroll
  for (int t = 0; t < 2; ++t)
#pragma unroll
    for (int nt = 0; nt < 8; ++nt) {
      int col = nt * 16 + l15;
      float b = be2[col], wa = Wa[col];
#pragma unroll
      for (int i = 0; i < 4; ++i) {
        float v = silu_f(acc[t][nt][i] + b);
        acc[t][nt][i] = v;
        part[t][i] += v * wa;
      }
    }
#pragma unroll
  for (int off = 1; off < 16; off <<= 1)
#pragma unroll
    for (int t = 0; t < 2; ++t)
#pragma unroll
      for (int i = 0; i < 4; ++i) part[t][i] += __shfl_xor(part[t][i], off, 64);
  float ba_f = ba[0];
#pragma unroll
  for (int t = 0; t < 2; ++t)
#pragma unroll
    for (int i = 0; i < 4; ++i) {
      float g = sigm_f(part[t][i] + ba_f);
#pragma unroll
      for (int nt = 0; nt < 8; ++nt) acc[t][nt][i] *= g;
    }
#pragma unroll
  for (int t = 0; t < 2; ++t)
#pragma unroll
    for (int nt = 0; nt < 8; ++nt)
#pragma unroll
      for (int i = 0; i < 4; ++i) xwrite(t, nt, i, acc[t][nt][i]);
#pragma unroll
  for (int t = 0; t < 2; ++t)
#pragma unroll
    for (int i = 0; i < 4; ++i) {
      size_t base = (size_t)dIdx[r0 + t * 16 + quad * 4 + i] * 128;
#pragma unroll
      for (int nt = 0; nt < 8; ++nt)
        atomicAdd(&m_agg[base + nt * 16 + l15], acc[t][nt][i]);
    }
#pragma unroll
  for (int t = 0; t < 2; ++t)
#pragma unroll
    for (int nt = 0; nt < 8; ++nt) acc[t][nt] = z4;

  // ---- coord layer: K=128, 4 chunks (global ids 14..17) ----
#pragma unroll
  for (int c = 0; c < 4; ++c) {
    int gi = 14 + c;
    if (c + 1 < 4) wload(Wc1t, 128, (c + 1) * 32);
    xread(c, aC);
    chunk_mfma(Wl + (gi & 1) * 4096, l15, quad, aC[0], aC[1], acc);
    if (c + 1 < 4) { wstore((gi + 1) & 1); SYNC(); }
  }
  float partc[2][4];
#pragma unroll
  for (int t = 0; t < 2; ++t)
#pragma unroll
    for (int i = 0; i < 4; ++i) partc[t][i] = 0.f;
#pragma unroll
  for (int t = 0; t < 2; ++t)
#pragma unroll
    for (int nt = 0; nt < 8; ++nt) {
      int col = nt * 16 + l15;
      float b = bc1[col], wc = Wc[col];
#pragma unroll
      for (int i = 0; i < 4; ++i) partc[t][i] += silu_f(acc[t][nt][i] + b) * wc;
    }
#pragma unroll
  for (int off = 1; off < 16; off <<= 1)
#pragma unroll
    for (int t = 0; t < 2; ++t)
#pragma unroll
      for (int i = 0; i < 4; ++i) partc[t][i] += __shfl_xor(partc[t][i], off, 64);
  if (l15 == 0) {
#pragma unroll
    for (int t = 0; t < 2; ++t)
#pragma unroll
      for (int i = 0; i < 4; ++i) {
        int row = r0 + t * 16 + quad * 4 + i;
        int d = dIdx[row];
        float c = partc[t][i];
        atomicAdd(&agg[d * 3 + 0], cdL[row][0] * c);
        atomicAdd(&agg[d * 3 + 1], cdL[row][1] * c);
        atomicAdd(&agg[d * 3 + 2], cdL[row][2] * c);
        atomicAdd(&cnt[d], 1.0f);
      }
  }
}

// ---------------- node kernel: 64 nodes/block (782 blocks), barrier-free ----------------
__global__ __launch_bounds__(256) void node_kernel(
    const bf16* __restrict__ nfb, const float* __restrict__ nf,
    const float* __restrict__ coords,
    const bf16* __restrict__ Wn1t, const float* __restrict__ bn1,
    const bf16* __restrict__ Wn2t, const float* __restrict__ bn2,
    const float* __restrict__ m_agg, const float* __restrict__ agg,
    const float* __restrict__ cnt,
    float* __restrict__ h_out, float* __restrict__ c_out) {
  __shared__ __align__(16) bf16 X[64 * 136];

  const int tid = threadIdx.x;
  const int lane = tid & 63;
  const int wv = tid >> 6;
  const int l15 = lane & 15;
  const int quad = lane >> 4;
  const int r0 = wv * 16;
  const int n0 = blockIdx.x * 64;

  if (tid < 64) {
    int n = n0 + tid;
    if (n < N_NODES) {
      float inv = 1.f / fmaxf(cnt[n], 1.f);
#pragma unroll
      for (int j = 0; j < 3; ++j)
        c_out[n * 3 + j] = coords[n * 3 + j] + agg[n * 3 + j] * inv;
    }
  }

  const floatx4 z4 = {0.f, 0.f, 0.f, 0.f};
  floatx4 acc[8];
#pragma unroll
  for (int nt = 0; nt < 8; ++nt) acc[nt] = z4;

  int nrow = n0 + r0 + l15;
  int nc = (nrow < N_NODES) ? nrow : 0;

  // ---- n1: K=256 (h | m_agg), B straight from L2-resident Wt ----
#pragma unroll
  for (int kc = 0; kc < 8; ++kc) {
    bf16x8 a;
    if (kc < 4) {
      a = *(const bf16x8*)(nfb + (size_t)nc * 128 + kc * 32 + quad * 8);
    } else {
      const float* p = m_agg + (size_t)nc * 128 + (kc - 4) * 32 + quad * 8;
      float4 u0 = *(const float4*)(p);
      float4 u1 = *(const float4*)(p + 4);
      a[0] = (bf16)u0.x; a[1] = (bf16)u0.y; a[2] = (bf16)u0.z; a[3] = (bf16)u0.w;
      a[4] = (bf16)u1.x; a[5] = (bf16)u1.y; a[6] = (bf16)u1.z; a[7] = (bf16)u1.w;
    }
#pragma unroll
    for (int nt = 0; nt < 8; ++nt) {
      bf16x8 b = *(const bf16x8*)(Wn1t + (size_t)(nt * 16 + l15) * 256 + kc * 32 + quad * 8);
      acc[nt] = MF(a, b, acc[nt]);
    }
  }
#pragma unroll
  for (int nt = 0; nt < 8; ++nt) {
    int col = nt * 16 + l15;
    float b = bn1[col];
#pragma unroll
    for (int i = 0; i < 4; ++i) {
      X[(r0 + quad * 4 + i) * 136 + col] = (bf16)silu_f(acc[nt][i] + b);
      acc[nt][i] = 0.f;
    }
  }

  // ---- n2: K=128 from X; residual from f32 nf ----
#pragma unroll
  for (int kc = 0; kc < 4; ++kc) {
    bf16x8 a = *(const bf16x8*)(X + (r0 + l15) * 136 + kc * 32 + quad * 8);
#pragma unroll
    for (int nt = 0; nt < 8; ++nt) {
      bf16x8 b = *(const bf16x8*)(Wn2t + (size_t)(nt * 16 + l15) * 128 + kc * 32 + quad * 8);
      acc[nt] = MF(a, b, acc[nt]);
    }
  }
#pragma unroll
  for (int nt = 0; nt < 8; ++nt) {
    int col = nt * 16 + l15;
    float b = bn2[col];
#pragma unroll
    for (int i = 0; i < 4; ++i) {
      int n = n0 + r0 + quad * 4 + i;
      if (n < N_NODES)
        h_out[(size_t)n * 128 + col] = nf[(size_t)n * 128 + col] + acc[nt][i] + b;
    }
  }
}

extern "C" void kernel_launch(void* const* d_in, const int* in_sizes, int n_in,
                              void* d_out, int out_size, void* d_ws, size_t ws_size,
                              hipStream_t stream) {
  const float* nf     = (const float*)d_in[0];
  const float* coords = (const float*)d_in[1];
  const float* ef     = (const float*)d_in[2];
  const float* We1    = (const float*)d_in[3];
  const float* be1    = (const float*)d_in[4];
  const float* We2    = (const float*)d_in[5];
  const float* be2    = (const float*)d_in[6];
  const float* Wn1    = (const float*)d_in[7];
  const float* bn1    = (const float*)d_in[8];
  const float* Wn2    = (const float*)d_in[9];
  const float* bn2    = (const float*)d_in[10];
  const float* Wc1    = (const float*)d_in[11];
  const float* bc1    = (const float*)d_in[12];
  const float* Wc     = (const float*)d_in[13];
  const float* Wa     = (const float*)d_in[14];
  const float* ba     = (const float*)d_in[15];
  const int*   src    = (const int*)d_in[16];
  const int*   dst    = (const int*)d_in[17];

  float* agg   = (float*)d_ws;                      // 3N
  float* cnt   = agg + (size_t)3 * N_NODES;         // N
  float* m_agg = cnt + N_NODES;                     // N*128
  bf16* nfb    = (bf16*)(m_agg + (size_t)N_NODES * 128);
  bf16* Wt     = nfb + (size_t)N_NODES * 128;       // 122880 bf16
  const int offE1 = 0;
  const int offE2 = 128 * 320;
  const int offC1 = offE2 + 128 * 128;
  const int offN1 = offC1 + 128 * 128;
  const int offN2 = offN1 + 128 * 256;

  size_t zb = ((size_t)3 * N_NODES + N_NODES + (size_t)N_NODES * 128) * sizeof(float);
  hipMemsetAsync(d_ws, 0, zb, stream);

  prep_nf<<<(N_NODES * 128) / (256 * 4), 256, 0, stream>>>(nf, nfb);
  TW tw;
  tw.s[0] = We1; tw.K[0] = 289; tw.Kp[0] = 320; tw.off[0] = offE1;
  tw.s[1] = We2; tw.K[1] = 128; tw.Kp[1] = 128; tw.off[1] = offE2;
  tw.s[2] = Wc1; tw.K[2] = 128; tw.Kp[2] = 128; tw.off[2] = offC1;
  tw.s[3] = Wn1; tw.K[3] = 256; tw.Kp[3] = 256; tw.off[3] = offN1;
  tw.s[4] = Wn2; tw.K[4] = 128; tw.Kp[4] = 128; tw.off[4] = offN2;
  prep_tw<<<480, 256, 0, stream>>>(tw, Wt);

  float* h_out = (float*)d_out;
  float* c_out = h_out + (size_t)N_NODES * 128;

  edge_kernel<<<N_EDGES / 128, 256, 0, stream>>>(
      nfb, coords, ef, Wt + offE1, be1, Wt + offE2, be2, Wt + offC1, bc1,
      Wc, Wa, ba, src, dst, m_agg, agg, cnt);
  node_kernel<<<(N_NODES + 63) / 64, 256, 0, stream>>>(
      nfb, nf, coords, Wt + offN1, bn1, Wt + offN2, bn2,
      m_agg, agg, cnt, h_out, c_out);
}